// Round 4
// baseline (3692.265 us; speedup 1.0000x reference)
//
#include <hip/hip_runtime.h>
#include <hip/hip_bf16.h>
#include <math.h>

#define BB 256
#define SS 128
#define EE 300
#define HH 300
#define G4 1200
#define DD 601
#define DP 608
#define ASZ 5
#define PP 3

typedef __attribute__((ext_vector_type(8))) short bf16x8s;
typedef __attribute__((ext_vector_type(4))) float f32x4;

union V16 { uint4 q; bf16x8s v; ushort u[8]; };

static __device__ __forceinline__ float sigf(float x){ return 1.0f/(1.0f+__expf(-x)); }
static __device__ __forceinline__ float bf2f(ushort u){ unsigned int x = ((unsigned int)u)<<16; return __uint_as_float(x); }
static __device__ __forceinline__ ushort f2bf(float f){ __hip_bfloat16 h = __float2bfloat16(f); return *reinterpret_cast<ushort*>(&h); }

// ---------------- lengths ----------------
__global__ void lengths_kernel(const int* __restrict__ traw, const int* __restrict__ tleft,
                               const int* __restrict__ aidx, int* __restrict__ lens){
  int b = blockIdx.x, tid = threadIdx.x; // 128 threads
  __shared__ int cnt[3];
  if(tid<3) cnt[tid]=0;
  __syncthreads();
  if(traw[b*SS+tid]!=0)  atomicAdd(&cnt[0],1);
  if(tleft[b*SS+tid]!=0) atomicAdd(&cnt[1],1);
  if(tid<ASZ && aidx[b*ASZ+tid]!=0) atomicAdd(&cnt[2],1);
  __syncthreads();
  if(tid==0){ lens[b]=cnt[0]; lens[BB+b]=cnt[1]; lens[2*BB+b]=cnt[2]; }
}

// ---------------- weight prep: Whh[1200][300] f32 -> Wn[dir][1280][320] bf16, n'=hl*4+g ----------------
__global__ void wprep_kernel(const float* __restrict__ whhf, const float* __restrict__ whhb,
                             __hip_bfloat16* __restrict__ Wn){
  int np = blockIdx.x;         // 0..1279
  int dir = blockIdx.y;        // 0..1
  int k = threadIdx.x;         // 0..319
  const float* src = dir ? whhb : whhf;
  int hl = np>>2, g = np&3;
  float v = (hl<300 && k<300) ? src[(size_t)(g*300+hl)*300 + k] : 0.0f;
  Wn[((size_t)dir*1280 + np)*320 + k] = __float2bfloat16(v);
}

// ---------------- w_ih prep: -> Wihn[dir][1280][320] bf16 (n'-interleaved) + biasn[dir][1280] ----------------
__global__ void wihprep_kernel(const float* __restrict__ wihf, const float* __restrict__ wihb,
                               const float* __restrict__ bihf, const float* __restrict__ bhhf,
                               const float* __restrict__ bihb, const float* __restrict__ bhhb,
                               __hip_bfloat16* __restrict__ Wihn, float* __restrict__ biasn){
  int np = blockIdx.x;         // 0..1279
  int dir = blockIdx.y;        // 0..1
  int k = threadIdx.x;         // 0..319
  const float* src = dir ? wihb : wihf;
  int hl = np>>2, g = np&3;
  int orig = g*300 + hl;
  float v = (hl<300 && k<300) ? src[(size_t)orig*EE + k] : 0.0f;
  Wihn[((size_t)dir*1280 + np)*320 + k] = __float2bfloat16(v);
  if(k==0){
    float bsum = 0.0f;
    if(hl<300) bsum = (dir ? (bihb[orig]+bhhb[orig]) : (bihf[orig]+bhhf[orig]));
    biasn[(size_t)dir*1280 + np] = bsum;
  }
}

// ---------------- input projection GEMM via MFMA (fused embedding gather), bf16 out ----------------
// Xp[dir][m][n'] = sum_k emb[idx[m]][k]*w_ih[orig(n')][k] + bias ; n' = hl*4+g
// tile 128m x 128n', K=320 in 5 chunks of 64. 512 threads = 8 waves (4m x 2n). dir = blockIdx.z.
__global__ __launch_bounds__(512)
void xproj_mfma(const int* __restrict__ idxrows, const float* __restrict__ emb,
                const __hip_bfloat16* __restrict__ Wihn, const float* __restrict__ biasn,
                __hip_bfloat16* __restrict__ Xp){
  __shared__ uint4 As16[128*8];
  __shared__ uint4 Bs16[128*8];
  __shared__ int rowidx[128];
  int dir = blockIdx.z;
  int m0 = blockIdx.y*128;
  int n0 = blockIdx.x*128;      // n' base
  const uint4* wihn4 = reinterpret_cast<const uint4*>(Wihn) + (size_t)dir*1280*40;
  __hip_bfloat16* Xpd = Xp + (size_t)dir*BB*SS*G4;
  int tid = threadIdx.x;
  int w = tid>>6, l = tid&63;
  int col = l&15, kgrp = l>>4;
  int wm = w>>1, wn = w&1;
  if(tid<128) rowidx[tid] = idxrows[m0+tid];
  f32x4 acc[2][4];
#pragma unroll
  for(int a=0;a<2;a++)
#pragma unroll
    for(int bq=0;bq<4;bq++){ acc[a][bq].x=0.f; acc[a][bq].y=0.f; acc[a][bq].z=0.f; acc[a][bq].w=0.f; }
  __syncthreads();  // rowidx ready
  for(int c=0;c<5;c++){
    if(c>0) __syncthreads();
    for(int i=tid;i<1024;i+=512){
      int r = i>>3, q = i&7;
      int kb = c*64 + q*8;
      // ---- A slot: gather emb row, f32 -> bf16 ----
      const float* ar = emb + (size_t)rowidx[r]*EE;
      V16 pk;
      if(kb+7 < 300){
        float4 f0 = *(const float4*)(ar+kb);
        float4 f1 = *(const float4*)(ar+kb+4);
        pk.u[0]=f2bf(f0.x); pk.u[1]=f2bf(f0.y); pk.u[2]=f2bf(f0.z); pk.u[3]=f2bf(f0.w);
        pk.u[4]=f2bf(f1.x); pk.u[5]=f2bf(f1.y); pk.u[6]=f2bf(f1.z); pk.u[7]=f2bf(f1.w);
      } else {
#pragma unroll
        for(int e=0;e<8;e++){ float v = (kb+e<300) ? ar[kb+e] : 0.0f; pk.u[e]=f2bf(v); }
      }
      As16[r*8 + (q^(r&7))] = pk.q;
      // ---- B slot: prepped bf16 table, straight copy ----
      Bs16[r*8 + (q^(r&7))] = wihn4[(size_t)(n0+r)*40 + c*8 + q];
    }
    __syncthreads();
#pragma unroll
    for(int kc=0;kc<2;kc++){
      int q = kc*4 + kgrp;
      V16 ua0, ua1, ub0, ub1, ub2, ub3;
      int ra0 = wm*32 + col, ra1 = wm*32 + 16 + col;
      ua0.q = As16[ra0*8 + (q^(ra0&7))];
      ua1.q = As16[ra1*8 + (q^(ra1&7))];
      int rb0 = wn*64 + col;
      ub0.q = Bs16[rb0*8 + (q^(rb0&7))];
      ub1.q = Bs16[(rb0+16)*8 + (q^((rb0+16)&7))];
      ub2.q = Bs16[(rb0+32)*8 + (q^((rb0+32)&7))];
      ub3.q = Bs16[(rb0+48)*8 + (q^((rb0+48)&7))];
      acc[0][0] = __builtin_amdgcn_mfma_f32_16x16x32_bf16(ua0.v, ub0.v, acc[0][0], 0,0,0);
      acc[1][0] = __builtin_amdgcn_mfma_f32_16x16x32_bf16(ua1.v, ub0.v, acc[1][0], 0,0,0);
      acc[0][1] = __builtin_amdgcn_mfma_f32_16x16x32_bf16(ua0.v, ub1.v, acc[0][1], 0,0,0);
      acc[1][1] = __builtin_amdgcn_mfma_f32_16x16x32_bf16(ua1.v, ub1.v, acc[1][1], 0,0,0);
      acc[0][2] = __builtin_amdgcn_mfma_f32_16x16x32_bf16(ua0.v, ub2.v, acc[0][2], 0,0,0);
      acc[1][2] = __builtin_amdgcn_mfma_f32_16x16x32_bf16(ua1.v, ub2.v, acc[1][2], 0,0,0);
      acc[0][3] = __builtin_amdgcn_mfma_f32_16x16x32_bf16(ua0.v, ub3.v, acc[0][3], 0,0,0);
      acc[1][3] = __builtin_amdgcn_mfma_f32_16x16x32_bf16(ua1.v, ub3.v, acc[1][3], 0,0,0);
    }
  }
  // epilogue: D row = kgrp*4+r, col = l&15 within each 16x16 tile
#pragma unroll
  for(int in=0;in<4;in++){
    int np = n0 + wn*64 + in*16 + col;
    if(np >= G4) continue;
    float bias = biasn[(size_t)dir*1280 + np];
#pragma unroll
    for(int im=0;im<2;im++){
#pragma unroll
      for(int r=0;r<4;r++){
        int m = m0 + wm*32 + im*16 + kgrp*4 + r;
        float v = acc[im][in][r] + bias;
        Xpd[(size_t)m*G4 + np] = __float2bfloat16(v);
      }
    }
  }
}

// ---------------- self-contained BiLSTM recurrence: 32 independent blocks, 1024 threads ----------------
// block = (dir, 16-batch group). 16 waves; wave w owns n' rows [w*80,w*80+80) = 5 MFMA n-tiles.
// Swapped-operand MFMA: D[n'][m] -> lane (col=m, kgrp) holds all 4 gates of (m, hl=w*20+i*4+kgrp).
// h: LDS bf16 double-buffer (XOR-swizzled). c: 5 VGPRs/lane. W: waves 0-1 from LDS cache, 2-14 stream L2.
__global__ __launch_bounds__(1024)
void lstm_self(const __hip_bfloat16* __restrict__ Xp, const __hip_bfloat16* __restrict__ Wn,
               float* __restrict__ mem, const int* __restrict__ lens){
  __shared__ uint4 Wlds[160*40];      // W rows n' [0,160), swizzled      102.4 KB
  __shared__ uint4 hbuf[2][640];      // h[16 m][320 k] bf16, swizzled     20.5 KB
  int bid = blockIdx.x;               // 32 blocks
  int dir = bid>>4, mbt = bid&15;
  int b0 = mbt*16;
  int tid = threadIdx.x;
  int w = tid>>6, l = tid&63;
  int col = l&15, kgrp = l>>4;
  int colx7 = col&7;

  const __hip_bfloat16* Xpd = Xp + (size_t)dir*BB*SS*G4;
  const uint4* wpD = reinterpret_cast<const uint4*>(Wn + (size_t)dir*1280*320);
  const uint4* wp  = wpD + (size_t)w*80*40;   // wave's W slice (rows w*80..+80)

  // init: zero both h buffers; stage W rows [0,160) into LDS (swizzled)
  for(int i=tid;i<1280;i+=1024) ((uint4*)hbuf)[i] = make_uint4(0,0,0,0);
  for(int i=tid;i<6400;i+=1024){
    int r = i/40, q = i - r*40;
    Wlds[r*40 + (q ^ (r&7))] = wpD[i];
  }

  int Lm = lens[b0+col];              // lane's batch length
  int tMax = 0;
  for(int m=0;m<16;m++){ int L = lens[b0+m]; tMax = L>tMax ? L : tMax; }

  float c_r[5] = {0.f,0.f,0.f,0.f,0.f};
  __syncthreads();

  for(int t=0;t<tMax;++t){
    int cur = t&1, nxt = cur^1;
    bool act = (t < Lm);
    int sx = dir ? (Lm-1-t) : t;
    // ---- per-lane Xp prefetch: gate quad (uint2 = 4 bf16) per tile ----
    uint2 xpr[5];
    if(act){
      const uint2* xb = reinterpret_cast<const uint2*>(Xpd + ((size_t)(b0+col)*SS + sx)*G4);
#pragma unroll
      for(int i=0;i<5;i++){
        int hl = w*20 + i*4 + kgrp;
        if(hl < 300) xpr[i] = xb[hl];
      }
    }
    // ---- MFMA: gates[n'][m] = W[n'][k] * h[m][k]^T ----
    f32x4 acc[5];
#pragma unroll
    for(int i=0;i<5;i++){ acc[i].x=0.f; acc[i].y=0.f; acc[i].z=0.f; acc[i].w=0.f; }
    if(w < 2){
      // LDS-cached W slice
#pragma unroll 2
      for(int kc=0;kc<10;kc++){
        V16 ua; ua.q = hbuf[cur][col*40 + ((kc*4+kgrp) ^ colx7)];
#pragma unroll
        for(int i=0;i<5;i++){
          int r = w*80 + i*16 + col;
          V16 wv; wv.q = Wlds[r*40 + ((kc*4+kgrp) ^ (r&7))];
          acc[i] = __builtin_amdgcn_mfma_f32_16x16x32_bf16(wv.v, ua.v, acc[i], 0,0,0);
        }
      }
    } else if(w < 15){
      // streamed W with register double-buffer
      V16 wr2[2][5];
#pragma unroll
      for(int i=0;i<5;i++) wr2[0][i].q = wp[(i*16+col)*40 + kgrp];
#pragma unroll
      for(int kc=0;kc<10;kc++){
        int pb = kc&1;
        if(kc<9){
#pragma unroll
          for(int i=0;i<5;i++) wr2[pb^1][i].q = wp[(i*16+col)*40 + (kc+1)*4 + kgrp];
        }
        V16 ua; ua.q = hbuf[cur][col*40 + ((kc*4+kgrp) ^ colx7)];
#pragma unroll
        for(int i=0;i<5;i++)
          acc[i] = __builtin_amdgcn_mfma_f32_16x16x32_bf16(wr2[pb][i].v, ua.v, acc[i], 0,0,0);
      }
    }
    // ---- pointwise LSTM cell (lane-local) + h write ----
#pragma unroll
    for(int i=0;i<5;i++){
      int hl = w*20 + i*4 + kgrp;
      if(hl >= 300) continue;
      int q = hl>>3, e = hl&7;
      ushort hbits;
      if(act){
        union{ uint2 u; ushort s[4]; } xv; xv.u = xpr[i];
        float ig = sigf(acc[i][0] + bf2f(xv.s[0]));
        float fg = sigf(acc[i][1] + bf2f(xv.s[1]));
        float gg = tanhf(acc[i][2] + bf2f(xv.s[2]));
        float og = sigf(acc[i][3] + bf2f(xv.s[3]));
        float cn = fg*c_r[i] + ig*gg;
        float hn = og*tanhf(cn);
        c_r[i] = cn;
        mem[((size_t)(b0+col)*SS + sx)*DP + dir*HH + hl] = hn;
        hbits = f2bf(hn);
      } else {
        hbits = reinterpret_cast<const ushort*>(&hbuf[cur][col*40 + (q ^ colx7)])[e];
      }
      reinterpret_cast<ushort*>(&hbuf[nxt][col*40 + (q ^ colx7)])[e] = hbits;
    }
    __syncthreads();
  }
}

// ---------------- location weighting + attention score (fused) ----------------
__global__ void loc_score_kernel(float* __restrict__ mem, const float* __restrict__ att_w,
                                 const int* __restrict__ lens, float* __restrict__ score){
  int bs = blockIdx.x;
  int b = bs/SS, s = bs%SS;
  int tid = threadIdx.x;  // 128
  int len = lens[b], left = lens[BB+b], alen = lens[2*BB+b];
  int a_start = left, a_end = left + alen;
  float uf = (s<a_start) ? (float)(s-a_start) : (s<a_end ? 0.f : (float)(s-a_end+1));
  float lf = (s<a_start) ? (float)(a_start-s) : (s<a_end ? 0.f : (float)(s-a_end+1));
  float w  = 1.f - lf/(float)len;
  float u  = (s<len) ? uf : 0.f;
  float partial = 0.f;
  float* row = mem + (size_t)bs*DP;
  if(s < len){
    for(int e=tid;e<600;e+=128){
      float v = row[e]*w;
      row[e] = v;
      partial += v*att_w[e];
    }
  }
  if(tid==0){
    row[600] = u;
    partial += u*att_w[600];
  }
  __shared__ float red[128];
  red[tid]=partial; __syncthreads();
  for(int s2=64;s2>0;s2>>=1){ if(tid<s2) red[tid]+=red[tid+s2]; __syncthreads(); }
  if(tid==0) score[bs]=red[0];
}

// ---------------- softmax over S + i_t = sum_s alpha*mem ----------------
__global__ void softmax_it_kernel(const float* __restrict__ score, const float* __restrict__ mem,
                                  float* __restrict__ i_t){
  int b = blockIdx.x, tid = threadIdx.x; // 128 threads
  __shared__ float sc[SS];
  __shared__ float red[SS];
  float v = score[b*SS+tid];
  red[tid]=v; __syncthreads();
  for(int s2=64;s2>0;s2>>=1){ if(tid<s2) red[tid]=fmaxf(red[tid],red[tid+s2]); __syncthreads(); }
  float m = red[0]; __syncthreads();
  float e = expf(v-m);
  sc[tid]=e; red[tid]=e; __syncthreads();
  for(int s2=64;s2>0;s2>>=1){ if(tid<s2) red[tid]+=red[tid+s2]; __syncthreads(); }
  float inv = 1.f/red[0]; __syncthreads();
  sc[tid] *= inv;
  __syncthreads();
  float acc[5]={0.f,0.f,0.f,0.f,0.f};
  for(int s=0;s<SS;s++){
    float a = sc[s];
    const float* row = mem + ((size_t)b*SS+s)*DP;
#pragma unroll
    for(int q=0;q<5;q++){
      int d = q*128+tid;
      if(d<DD) acc[q] += a*row[d];
    }
  }
#pragma unroll
  for(int q=0;q<5;q++){
    int d = q*128+tid;
    if(d<DD) i_t[(size_t)b*DP+d] = acc[q];
  }
}

// ---------------- gi = i_t @ gru_w_ih^T + gru_b_ih ----------------
__global__ __launch_bounds__(320)
void gi_kernel(const float* __restrict__ i_t, const float* __restrict__ gwih,
               const float* __restrict__ gbih, float* __restrict__ gi){
  int b = blockIdx.x, tid = threadIdx.x; // 320
  __shared__ float it[DD];
  for(int d=tid;d<DD;d+=320) it[d]=i_t[(size_t)b*DP+d];
  __syncthreads();
  for(int n=tid;n<900;n+=320){
    const float* wr = gwih + (size_t)n*DD;
    float s=0.f;
    for(int d=0;d<DD;d++) s += wr[d]*it[d];
    gi[(size_t)b*900+n] = s + gbih[n];
  }
}

// ---------------- 3 GRU hops + dense (fused) ----------------
__global__ __launch_bounds__(320)
void hops_kernel(const float* __restrict__ gi, const float* __restrict__ gwhh,
                 const float* __restrict__ gbhh, const float* __restrict__ dw,
                 const float* __restrict__ db, float* __restrict__ out){
  int b = blockIdx.x, tid = threadIdx.x; // 320
  __shared__ float et_s[HH];
  float gir=0.f,giz=0.f,gin=0.f,bhr=0.f,bhz=0.f,bhn=0.f;
  if(tid<300){
    et_s[tid]=0.f;
    gir = gi[(size_t)b*900+tid];
    giz = gi[(size_t)b*900+300+tid];
    gin = gi[(size_t)b*900+600+tid];
    bhr = gbhh[tid]; bhz = gbhh[300+tid]; bhn = gbhh[600+tid];
  }
  __syncthreads();
  for(int hop=0;hop<3;hop++){
    float etn=0.f;
    if(tid<300){
      const float* wr = gwhh + (size_t)tid*HH;
      const float* wz = gwhh + (size_t)(300+tid)*HH;
      const float* wn = gwhh + (size_t)(600+tid)*HH;
      float ghr=bhr, ghz=bhz, ghn=bhn;
      for(int d=0;d<HH;d++){
        float e = et_s[d];
        ghr += wr[d]*e; ghz += wz[d]*e; ghn += wn[d]*e;
      }
      float r = sigf(gir+ghr);
      float z = sigf(giz+ghz);
      float n = tanhf(gin + r*ghn);
      etn = (1.f-z)*n + z*et_s[tid];
    }
    __syncthreads();
    if(tid<300) et_s[tid]=etn;
    __syncthreads();
  }
  if(tid<192){
    int p = tid/64, lane = tid%64;
    float partial = 0.f;
    for(int e=lane;e<HH;e+=64) partial += et_s[e]*dw[(size_t)p*HH+e];
    for(int off=32;off>0;off>>=1) partial += __shfl_down(partial, off);
    if(lane==0) out[(size_t)b*PP+p] = partial + db[p];
  }
}

extern "C" void kernel_launch(void* const* d_in, const int* in_sizes, int n_in,
                              void* d_out, int out_size, void* d_ws, size_t ws_size,
                              hipStream_t stream){
  (void)in_sizes; (void)n_in; (void)out_size; (void)ws_size;
  const int*   traw  = (const int*)  d_in[0];
  const int*   aidx  = (const int*)  d_in[1];
  const int*   tleft = (const int*)  d_in[2];
  const float* emb   = (const float*)d_in[3];
  const float* wihf  = (const float*)d_in[4];
  const float* whhf  = (const float*)d_in[5];
  const float* bihf  = (const float*)d_in[6];
  const float* bhhf  = (const float*)d_in[7];
  const float* wihb  = (const float*)d_in[8];
  const float* whhb  = (const float*)d_in[9];
  const float* bihb  = (const float*)d_in[10];
  const float* bhhb  = (const float*)d_in[11];
  const float* attw  = (const float*)d_in[12];
  // d_in[13] att_b unused (cancels in softmax)
  const float* gwih  = (const float*)d_in[14];
  const float* gwhh  = (const float*)d_in[15];
  const float* gbih  = (const float*)d_in[16];
  const float* gbhh  = (const float*)d_in[17];
  const float* dw    = (const float*)d_in[18];
  const float* db    = (const float*)d_in[19];
  float* out = (float*)d_out;

  char* ws = (char*)d_ws;
  size_t off = 0;
  auto alloc = [&](size_t bytes)->void*{
    void* p = ws + off;
    off += (bytes + 255) & ~(size_t)255;
    return p;
  };
  __hip_bfloat16* Xp   = (__hip_bfloat16*)alloc((size_t)2*BB*SS*G4*2);   // 157.3 MB (n'-interleaved)
  float* mem   = (float*)alloc((size_t)BB*SS*DP*4);                      // 79.7 MB
  __hip_bfloat16* Wn   = (__hip_bfloat16*)alloc((size_t)2*1280*320*2);   // 1.64 MB
  __hip_bfloat16* Wihn = (__hip_bfloat16*)alloc((size_t)2*1280*320*2);   // 1.64 MB
  float* biasn = (float*)alloc((size_t)2*1280*4);
  int*   lens  = (int*)  alloc(3*BB*sizeof(int));
  float* score = (float*)alloc((size_t)BB*SS*4);
  float* i_t   = (float*)alloc((size_t)BB*DP*4);
  float* gi    = (float*)alloc((size_t)BB*900*4);

  hipMemsetAsync(mem, 0, (size_t)BB*SS*DP*4, stream);

  lengths_kernel<<<BB,128,0,stream>>>(traw, tleft, aidx, lens);
  wprep_kernel<<<dim3(1280,2),320,0,stream>>>(whhf, whhb, Wn);
  wihprep_kernel<<<dim3(1280,2),320,0,stream>>>(wihf, wihb, bihf, bhhf, bihb, bhhb, Wihn, biasn);

  xproj_mfma<<<dim3(10,256,2),512,0,stream>>>(traw, emb, Wihn, biasn, Xp);

  lstm_self<<<32,1024,0,stream>>>(Xp, Wn, mem, lens);

  loc_score_kernel<<<BB*SS,128,0,stream>>>(mem, attw, lens, score);
  softmax_it_kernel<<<BB,128,0,stream>>>(score, mem, i_t);
  gi_kernel<<<BB,320,0,stream>>>(i_t, gwih, gbih, gi);
  hops_kernel<<<BB,320,0,stream>>>(gi, gwhh, gbhh, dw, db, out);
}